// Round 3
// baseline (320.728 us; speedup 1.0000x reference)
//
#include <hip/hip_runtime.h>

#define KW   31
#define R    15
#define NP   32
#define HH   512
#define WW   512
#define NB   4

#define TX   16              // thread groups in x (each handles 4 px)
#define TY   16              // thread rows
#define PXW  (TX * 4)        // 64 pixels wide per block
#define EXT_Y (TY + 2*R)     // 46
#define EXT_X (PXW + 2*R)    // 94
#define XSTRIDE 104          // floats; mult of 4 (16B align), ≡8 mod 32 banks

__global__ __launch_bounds__(256, 2) void defocus_kernel(
    const float* __restrict__ sharp, const float* __restrict__ coc_map,
    float* __restrict__ out)
{
    __shared__ float gT[KW][NP];     // gT[tap][plane]
    __shared__ float bnd[KW];
    __shared__ float tile[3][EXT_Y][XSTRIDE];

    const int tid = threadIdx.x;

    // ---- per-plane 1-D Gaussian weights (zero-padded to 31, centered at R) ----
    if (tid < NP) {
        const int p = tid;
        const double step = 50.0 / 31.0;
        const float pv = (p == 31) ? 50.0f : (float)((double)p * step);
        #pragma unroll
        for (int j = 0; j < KW; ++j) gT[j][p] = 0.0f;
        if (pv < 0.5f) {
            gT[R][p] = 1.0f;
        } else {
            const double coc   = (double)pv;
            const double sigma = coc / 2.355;
            int k = (int)(2.0 * coc + 1.0);
            if ((k & 1) == 0) k += 1;
            if (k > KW) k = KW;
            const int half = k >> 1;
            float s = 0.0f;
            for (int j = 0; j < k; ++j) {
                double c = (double)(j - half);
                s += (float)exp(-(c * c) / (2.0 * sigma * sigma));
            }
            for (int j = 0; j < k; ++j) {
                double c = (double)(j - half);
                gT[R - half + j][p] = (float)exp(-(c * c) / (2.0 * sigma * sigma)) / s;
            }
        }
    }
    // ---- bucket boundaries, bit-exact float32((planes[i]+planes[i+1])/2) ----
    if (tid < KW) {
        const double step = 50.0 / 31.0;
        const float pa = (float)((double)tid * step);
        const float pb = (tid == 30) ? 50.0f : (float)((double)(tid + 1) * step);
        bnd[tid] = (pa + pb) * 0.5f;
    }

    // ---- stage input tile (+halo), zero outside image ----
    const int bx = blockIdx.x, by = blockIdx.y, bb = blockIdx.z;
    const int x0 = bx * PXW - R, y0 = by * TY - R;
    for (int idx = tid; idx < EXT_Y * EXT_X; idx += 256) {
        const int r = idx / EXT_X, c = idx - r * EXT_X;
        const int gy = y0 + r, gx = x0 + c;
        const bool ok = ((unsigned)gy < HH) && ((unsigned)gx < WW);
        #pragma unroll
        for (int ch = 0; ch < 3; ++ch) {
            tile[ch][r][c] = ok ? sharp[(((size_t)bb * 3 + ch) * HH + gy) * WW + gx] : 0.0f;
        }
    }
    __syncthreads();

    // ---- this thread's 4 pixels ----
    const int tx = tid & (TX - 1), ty = tid >> 4;
    const int ox = bx * PXW + 4 * tx, oy = by * TY + ty;

    // plane select per pixel (exact reference semantics: count coc > bnd[k])
    const float4 coc4 = *(const float4*)&coc_map[((size_t)bb * HH + oy) * WW + ox];
    const float cocv[4] = {coc4.x, coc4.y, coc4.z, coc4.w};
    int plane[4];
    #pragma unroll
    for (int j = 0; j < 4; ++j) {
        int p = 0;
        #pragma unroll
        for (int k = 0; k < KW; ++k) p += (cocv[j] > bnd[k]) ? 1 : 0;
        plane[j] = p;
    }

    // hoist each pixel's x-weights; Gaussian symmetric: g[R-d]==g[R+d] -> 16 uniques
    float gv[4][16];
    #pragma unroll
    for (int j = 0; j < 4; ++j)
        #pragma unroll
        for (int d = 0; d < 16; ++d) gv[j][d] = gT[R + d][plane[j]];

    // ---- separable accumulation; window shared by the 4 pixels ----
    #pragma unroll 1
    for (int ch = 0; ch < 3; ++ch) {
        float acc[4] = {0.f, 0.f, 0.f, 0.f};
        #pragma unroll 1
        for (int dy = 0; dy < KW; ++dy) {
            const float* rowp = &tile[ch][ty + dy][4 * tx];   // 16B aligned
            float win[36];
            #pragma unroll
            for (int k = 0; k < 9; ++k)
                *(float4*)&win[4 * k] = *(const float4*)&rowp[4 * k];
            // y-weight from LDS (no dynamic index into private arrays!)
            float wy[4];
            #pragma unroll
            for (int j = 0; j < 4; ++j) wy[j] = gT[dy][plane[j]];
            #pragma unroll
            for (int j = 0; j < 4; ++j) {
                float r = gv[j][0] * win[j + R];
                #pragma unroll
                for (int d = 1; d < 16; ++d)
                    r = fmaf(gv[j][d], win[j + R - d] + win[j + R + d], r);
                acc[j] = fmaf(wy[j], r, acc[j]);
            }
        }
        float4 o4 = make_float4(acc[0], acc[1], acc[2], acc[3]);
        *(float4*)&out[(((size_t)bb * 3 + ch) * HH + oy) * WW + ox] = o4;
    }
}

extern "C" void kernel_launch(void* const* d_in, const int* in_sizes, int n_in,
                              void* d_out, int out_size, void* d_ws, size_t ws_size,
                              hipStream_t stream) {
    const float* sharp = (const float*)d_in[0];
    const float* coc   = (const float*)d_in[1];
    float* outp        = (float*)d_out;
    dim3 grid(WW / PXW, HH / TY, NB);
    defocus_kernel<<<grid, dim3(256), 0, stream>>>(sharp, coc, outp);
}

// Round 4
// 243.539 us; speedup vs baseline: 1.3169x; 1.3169x over previous
//
#include <hip/hip_runtime.h>

#define KW   31
#define R    15
#define NP   32
#define HH   512
#define WW   512
#define NB   4

#define TX   16              // thread groups in x (each handles 4 px)
#define TY   16              // thread rows
#define PXW  (TX * 4)        // 64 pixels wide per block
#define EXT_Y (TY + 2*R)     // 46
#define EXT_X (PXW + 2*R)    // 94
#define XSTRIDE 97           // ODD: no b128 vectorization possible; rows land at
                             // bank offsets {0,1,2,3} mod 4 -> disjoint sets, uniform 2-way (free)

__global__ __launch_bounds__(256, 2) void defocus_kernel(
    const float* __restrict__ sharp, const float* __restrict__ coc_map,
    float* __restrict__ out)
{
    __shared__ float gT[KW][NP];     // gT[tap][plane]
    __shared__ float bnd[KW];
    __shared__ float tile[3][EXT_Y][XSTRIDE];

    const int tid = threadIdx.x;

    // ---- per-plane 1-D Gaussian weights (zero-padded to 31, centered at R) ----
    if (tid < NP) {
        const int p = tid;
        const double step = 50.0 / 31.0;
        const float pv = (p == 31) ? 50.0f : (float)((double)p * step);
        #pragma unroll
        for (int j = 0; j < KW; ++j) gT[j][p] = 0.0f;
        if (pv < 0.5f) {
            gT[R][p] = 1.0f;
        } else {
            const double coc   = (double)pv;
            const double sigma = coc / 2.355;
            int k = (int)(2.0 * coc + 1.0);
            if ((k & 1) == 0) k += 1;
            if (k > KW) k = KW;
            const int half = k >> 1;
            float s = 0.0f;
            for (int j = 0; j < k; ++j) {
                double c = (double)(j - half);
                s += (float)exp(-(c * c) / (2.0 * sigma * sigma));
            }
            for (int j = 0; j < k; ++j) {
                double c = (double)(j - half);
                gT[R - half + j][p] = (float)exp(-(c * c) / (2.0 * sigma * sigma)) / s;
            }
        }
    }
    // ---- bucket boundaries, bit-exact float32((planes[i]+planes[i+1])/2) ----
    if (tid < KW) {
        const double step = 50.0 / 31.0;
        const float pa = (float)((double)tid * step);
        const float pb = (tid == 30) ? 50.0f : (float)((double)(tid + 1) * step);
        bnd[tid] = (pa + pb) * 0.5f;
    }

    // ---- stage input tile (+halo), zero outside image ----
    const int bx = blockIdx.x, by = blockIdx.y, bb = blockIdx.z;
    const int x0 = bx * PXW - R, y0 = by * TY - R;
    for (int idx = tid; idx < EXT_Y * EXT_X; idx += 256) {
        const int r = idx / EXT_X, c = idx - r * EXT_X;
        const int gy = y0 + r, gx = x0 + c;
        const bool ok = ((unsigned)gy < HH) && ((unsigned)gx < WW);
        #pragma unroll
        for (int ch = 0; ch < 3; ++ch) {
            tile[ch][r][c] = ok ? sharp[(((size_t)bb * 3 + ch) * HH + gy) * WW + gx] : 0.0f;
        }
    }
    __syncthreads();

    // ---- this thread's 4 pixels ----
    const int tx = tid & (TX - 1), ty = tid >> 4;
    const int ox = bx * PXW + 4 * tx, oy = by * TY + ty;

    // plane select per pixel (exact reference semantics: count coc > bnd[k])
    const float4 coc4 = *(const float4*)&coc_map[((size_t)bb * HH + oy) * WW + ox];
    const float cocv[4] = {coc4.x, coc4.y, coc4.z, coc4.w};
    int plane[4];
    #pragma unroll
    for (int j = 0; j < 4; ++j) {
        int p = 0;
        #pragma unroll
        for (int k = 0; k < KW; ++k) p += (cocv[j] > bnd[k]) ? 1 : 0;
        plane[j] = p;
    }

    // hoist each pixel's x-weights; Gaussian symmetric: g[R-d]==g[R+d] -> 16 uniques
    float gv[4][16];
    #pragma unroll
    for (int j = 0; j < 4; ++j)
        #pragma unroll
        for (int d = 0; d < 16; ++d) gv[j][d] = gT[R + d][plane[j]];

    // ---- separable accumulation; window shared by the 4 pixels ----
    #pragma unroll 1
    for (int ch = 0; ch < 3; ++ch) {
        float acc[4] = {0.f, 0.f, 0.f, 0.f};
        #pragma unroll 1
        for (int dy = 0; dy < KW; ++dy) {
            const float* rowp = &tile[ch][ty + dy][4 * tx];
            float win[36];
            #pragma unroll
            for (int k = 0; k < 36; ++k) win[k] = rowp[k];   // b32/read2 only (odd stride)
            // y-weight from LDS (no dynamic index into private arrays)
            float wy[4];
            #pragma unroll
            for (int j = 0; j < 4; ++j) wy[j] = gT[dy][plane[j]];
            #pragma unroll
            for (int j = 0; j < 4; ++j) {
                float r = gv[j][0] * win[j + R];
                #pragma unroll
                for (int d = 1; d < 16; ++d)
                    r = fmaf(gv[j][d], win[j + R - d] + win[j + R + d], r);
                acc[j] = fmaf(wy[j], r, acc[j]);
            }
        }
        float4 o4 = make_float4(acc[0], acc[1], acc[2], acc[3]);
        *(float4*)&out[(((size_t)bb * 3 + ch) * HH + oy) * WW + ox] = o4;
    }
}

extern "C" void kernel_launch(void* const* d_in, const int* in_sizes, int n_in,
                              void* d_out, int out_size, void* d_ws, size_t ws_size,
                              hipStream_t stream) {
    const float* sharp = (const float*)d_in[0];
    const float* coc   = (const float*)d_in[1];
    float* outp        = (float*)d_out;
    dim3 grid(WW / PXW, HH / TY, NB);
    defocus_kernel<<<grid, dim3(256), 0, stream>>>(sharp, coc, outp);
}